// Round 7
// baseline (133.651 us; speedup 1.0000x reference)
//
#include <hip/hip_runtime.h>

// ComplexLinearAndLeakyReLU — round 7: persistent block, cross-group pipelining.
// 256 blocks x 1024 threads; each block processes GROUPS=4 site-groups (NT=16).
// Double-buffered Z in LDS (2 x 74.5 KB = 149 KB, 1 block/CU, 16 waves/CU).
// Per group g: [issue HBM loads g+1] -> GEMM1(g) -> bar -> stage Y -> bar ->
//              GEMM2(g)+epilogue -> [basis+store g+1 -> other buffer] -> bar.
// Math identical to rounds 5/6 (fp16 MFMA, reciprocal basis, np-exact epilogue).

constexpr float EPSf  = 1e-6f;
constexpr int Bdim = 8, Cdim = 2048, Edim = 256, Fdim = 256;
constexpr int NT  = 16;            // sites per group
constexpr int KC1 = 24;            // GEMM1 K chunks of 32 (K=768)
constexpr int KC2 = 8;             // GEMM2 K chunks of 32 (K=256)
constexpr int ZLD = 776;           // Zt row stride in halves (768 + 8 pad)
constexpr int YLD = 264;           // Yt row stride in halves (256 + 8 pad)
constexpr int ZSZ = 48 * ZLD;      // halves per Z buffer (74,496 B)
constexpr int GROUPS = 4;          // 1024 groups / 256 blocks
constexpr int M_ROWS = KC1 * 16 * 64;
constexpr int W_ROWS = KC2 * 16 * 64;

typedef __attribute__((ext_vector_type(8))) _Float16 half8;
typedef __attribute__((ext_vector_type(4))) _Float16 half4;
typedef __attribute__((ext_vector_type(4))) float    f32x4;

// ---- basis + abc: reciprocal-based (3 divides, 2 sqrts), FMA allowed ----
__device__ __forceinline__ void basis_abc(float Xx, float Xy, float Xz,
                                          float Jx, float Jy, float Jz,
                                          float* a, float* bb, float* cc)
{
    const float jn  = sqrtf(Jx*Jx + Jy*Jy + Jz*Jz) + EPSf;
    const float rj  = 1.0f / jn;
    const float nJx = Jx * rj, nJy = Jy * rj, nJz = Jz * rj;
    const float h   = nJx*nJx + nJy*nJy;
    const float Uz  = -h / (nJz + EPSf);
    const float un  = sqrtf(h + Uz*Uz) + EPSf;
    const float ru  = 1.0f / un;
    const float nUx = nJx * ru, nUy = nJy * ru, nUz = Uz * ru;
    const float nVx = nUy*nJz - nUz*nJy;
    const float nVy = nUz*nJx - nUx*nJz;
    const float nVz = nUx*nJy - nUy*nJx;
    const float r0 = nUx*Xx + nVx*Xy + nJx*Xz;
    const float r1 = nUy*Xx + nVy*Xy + nJy*Xz;
    const float r2 = nUz*Xx + nVz*Xy + nJz*Xz;
    a[0]  = nUx*r0 + nUy*r1;   a[1]  = nVx*r0 + nVy*r1;   a[2]  = nJx*r0 + nJy*r1;
    bb[0] = nUy*r0 - nUx*r1;   bb[1] = nVy*r0 - nVx*r1;   bb[2] = nJy*r0 - nJx*r1;
    cc[0] = nUz*r2;            cc[1] = nVz*r2;            cc[2] = nJz*r2;
}

// ---------------- weight prep: fp32 -> fp16 in MFMA A-fragment order ----------------
__global__ __launch_bounds__(256)
void prep_weights_f16(const float* __restrict__ Ap, const float* __restrict__ Bp,
                      const float* __restrict__ Cp, const float* __restrict__ Wp,
                      _Float16* __restrict__ ws)
{
    const int tid = blockIdx.x * 256 + threadIdx.x;
    const bool isW = tid >= M_ROWS;
    const int row = isW ? tid - M_ROWS : tid;
    const int l   = row & 63;
    const int ft  = (row >> 6) & 15;
    const int kc  = row >> 10;
    const int f   = ft * 16 + (l & 15);
    const int k0  = kc * 32 + ((l >> 4) << 3);

    const float* src;
    int e0;
    if (isW)            { src = Wp; e0 = k0; }
    else if (k0 < 256)  { src = Ap; e0 = k0; }
    else if (k0 < 512)  { src = Bp; e0 = k0 - 256; }
    else                { src = Cp; e0 = k0 - 512; }

    const float* p = src + f * 256 + e0;
    half8 v;
    #pragma unroll
    for (int j = 0; j < 8; ++j) v[j] = (_Float16)p[j];

    _Float16* dst = ws + (isW ? (size_t)M_ROWS * 8 : 0);
    *reinterpret_cast<half8*>(dst + (size_t)row * 8) = v;
}

// ---------------- persistent fused main kernel: 1024 threads = 16 waves ----------------
__global__ __launch_bounds__(1024, 4)
void fused_mfma_f16(const float* __restrict__ Xp, const float* __restrict__ Jp,
                    const _Float16* __restrict__ wsM, const _Float16* __restrict__ wsW,
                    float* __restrict__ outp)
{
    __shared__ __align__(16) _Float16 lds[2 * ZSZ];   // 148,992 B -> 1 block/CU

    const int t     = threadIdx.x;
    const int site  = t >> 6;          // 0..15: phase-1 site; also GEMM f-tile (wid)
    const int equad = t & 63;
    const int e0    = equad * 4;
    const int wid   = site;
    const int l     = t & 63;
    const int lr    = l & 15;
    const int lk    = (l >> 4) * 8;
    const int g0    = blockIdx.x * GROUPS;

    float4 xv[3], jv[3];               // in-flight next-group inputs

    auto LOADIN = [&](int g) {
        const long sg = (long)(g0 + g) * NT + site;   // flattened b*Cdim + c
        const float4* X4 = reinterpret_cast<const float4*>(Xp) + sg * 192 + equad * 3;
        const float4* J4 = reinterpret_cast<const float4*>(Jp) + sg * 192 + equad * 3;
        xv[0] = X4[0]; xv[1] = X4[1]; xv[2] = X4[2];
        jv[0] = J4[0]; jv[1] = J4[1]; jv[2] = J4[2];
    };

    auto BASIS_STORE = [&](int g) {
        _Float16* Z = lds + (g & 1) * ZSZ;
        const float xf[12] = {xv[0].x,xv[0].y,xv[0].z,xv[0].w,
                              xv[1].x,xv[1].y,xv[1].z,xv[1].w,
                              xv[2].x,xv[2].y,xv[2].z,xv[2].w};
        const float jf[12] = {jv[0].x,jv[0].y,jv[0].z,jv[0].w,
                              jv[1].x,jv[1].y,jv[1].z,jv[1].w,
                              jv[2].x,jv[2].y,jv[2].z,jv[2].w};
        half4 za[3], zb[3], zc[3];
        #pragma unroll
        for (int ee = 0; ee < 4; ++ee) {
            float a[3], bb[3], cc[3];
            basis_abc(xf[3*ee], xf[3*ee+1], xf[3*ee+2],
                      jf[3*ee], jf[3*ee+1], jf[3*ee+2], a, bb, cc);
            #pragma unroll
            for (int i = 0; i < 3; ++i) {
                za[i][ee] = (_Float16)a[i];
                zb[i][ee] = (_Float16)bb[i];
                zc[i][ee] = (_Float16)cc[i];
            }
        }
        // Zt[n = i*16+s][k = m*256+e]
        #pragma unroll
        for (int i = 0; i < 3; ++i) {
            _Float16* rowp = Z + (i * NT + site) * ZLD;
            *reinterpret_cast<half4*>(rowp +       e0) = za[i];
            *reinterpret_cast<half4*>(rowp + 256 + e0) = zb[i];
            *reinterpret_cast<half4*>(rowp + 512 + e0) = zc[i];
        }
    };

    // ---- prologue: group 0 ----
    LOADIN(0);
    BASIS_STORE(0);
    __syncthreads();

    const half8* Mf = reinterpret_cast<const half8*>(wsM);
    const half8* Wf = reinterpret_cast<const half8*>(wsW);

    for (int g = 0; g < GROUPS; ++g) {
        const _Float16* Z = lds + (g & 1) * ZSZ;

        if (g + 1 < GROUPS) LOADIN(g + 1);   // HBM loads in flight across GEMM1

        // ---- GEMM1: Yacc[nt] over K=768, wave owns 1 f-tile ----
        f32x4 Yacc[3];
        #pragma unroll
        for (int nt = 0; nt < 3; ++nt) Yacc[nt] = f32x4{0.f, 0.f, 0.f, 0.f};

        for (int kc = 0; kc < KC1; ++kc) {
            half8 af = Mf[(kc * 16 + wid) * 64 + l];
            half8 zf[3];
            #pragma unroll
            for (int nt = 0; nt < 3; ++nt)
                zf[nt] = *reinterpret_cast<const half8*>(&Z[(nt * NT + lr) * ZLD + kc * 32 + lk]);
            #pragma unroll
            for (int nt = 0; nt < 3; ++nt)
                Yacc[nt] = __builtin_amdgcn_mfma_f32_16x16x32_f16(af, zf[nt], Yacc[nt], 0, 0, 0);
        }
        __syncthreads();   // all Z reads done; buffer free for Yt alias

        // ---- stage Y as fp16 Yt[col][row] (aliases current Z buffer) ----
        _Float16* Yt = lds + (g & 1) * ZSZ;
        {
            const int row = wid * 16 + (l >> 4) * 4;
            #pragma unroll
            for (int nt = 0; nt < 3; ++nt) {
                const int col = nt * NT + lr;
                half4 v = { (_Float16)Yacc[nt][0], (_Float16)Yacc[nt][1],
                            (_Float16)Yacc[nt][2], (_Float16)Yacc[nt][3] };
                *reinterpret_cast<half4*>(&Yt[col * YLD + row]) = v;
            }
        }
        __syncthreads();

        // ---- GEMM2: Dacc[nt] over K=256 ----
        f32x4 Dacc[3];
        #pragma unroll
        for (int nt = 0; nt < 3; ++nt) Dacc[nt] = f32x4{0.f, 0.f, 0.f, 0.f};

        for (int kc = 0; kc < KC2; ++kc) {
            half8 wf = Wf[(kc * 16 + wid) * 64 + l];
            half8 yf[3];
            #pragma unroll
            for (int nt = 0; nt < 3; ++nt)
                yf[nt] = *reinterpret_cast<const half8*>(&Yt[(nt * NT + lr) * YLD + kc * 32 + lk]);
            #pragma unroll
            for (int nt = 0; nt < 3; ++nt)
                Dacc[nt] = __builtin_amdgcn_mfma_f32_16x16x32_f16(wf, yf[nt], Dacc[nt], 0, 0, 0);
        }

        // ---- epilogue: leaky projection (np-exact op order), direct stores ----
        {
            const int s0g   = (g0 + g) * NT;
            const int b     = s0g >> 11;
            const int c0    = s0g & (Cdim - 1);
            const int fbase = wid * 16 + (l >> 4) * 4;
            #pragma unroll
            for (int r = 0; r < 4; ++r) {
#pragma clang fp contract(off)
                const float x0 = Yacc[0][r], x1 = Yacc[1][r], x2 = Yacc[2][r];
                const float d0 = Dacc[0][r], d1 = Dacc[1][r], d2 = Dacc[2][r];
                const float dot = (x0*d0 + x1*d1) + x2*d2;
                const float dns = (d0*d0 + d1*d1) + d2*d2;
                const float sc  = dot / (dns + EPSf);
                const bool  pos = (dot >= 0.f);
                const int f = fbase + r;
                const long obase = ((long)(b * Fdim + f) * 3) * Cdim + c0 + lr;
                const float c0v = pos ? x0 : (x0 - sc*d0);
                const float c1v = pos ? x1 : (x1 - sc*d1);
                const float c2v = pos ? x2 : (x2 - sc*d2);
                outp[obase + 0 * Cdim] = 0.2f*x0 + 0.8f*c0v;
                outp[obase + 1 * Cdim] = 0.2f*x1 + 0.8f*c1v;
                outp[obase + 2 * Cdim] = 0.2f*x2 + 0.8f*c2v;
            }
        }

        // ---- produce next group's Z into the other buffer ----
        if (g + 1 < GROUPS) BASIS_STORE(g + 1);
        __syncthreads();
    }
}

// ---------------- fp32 fallback if ws too small ----------------
__device__ __forceinline__ float comp(const float4& v, int k) {
    return k == 0 ? v.x : k == 1 ? v.y : k == 2 ? v.z : v.w;
}

__global__ __launch_bounds__(256)
void fused_cl_lrelu_fp32(const float* __restrict__ Xp, const float* __restrict__ Jp,
                         const float* __restrict__ Ap, const float* __restrict__ Bp,
                         const float* __restrict__ Cp, const float* __restrict__ Wp,
                         float* __restrict__ outp)
{
    __shared__ float4 sabc[4 * Edim * 3];
    __shared__ float  ylds[4 * 3][Fdim];

    const int t   = threadIdx.x;
    const int s0  = blockIdx.x * 4;
    const int b   = s0 / Cdim;
    const int c0  = s0 % Cdim;

    #pragma unroll
    for (int r = 0; r < 4; ++r) {
        const int e  = t;
        const int idx = ((b * Cdim + c0 + r) * Edim + e) * 3;
        float a[3], bb[3], cc[3];
        basis_abc(Xp[idx], Xp[idx+1], Xp[idx+2], Jp[idx], Jp[idx+1], Jp[idx+2], a, bb, cc);
        const int base = (r * Edim + e) * 3;
        sabc[base + 0] = make_float4(a[0], a[1], a[2], bb[0]);
        sabc[base + 1] = make_float4(bb[1], bb[2], cc[0], cc[1]);
        sabc[base + 2] = make_float4(cc[2], 0.f, 0.f, 0.f);
    }
    __syncthreads();

    const int fl = t & 63;
    const int cg = t >> 6;
    float Y[4][3];
    #pragma unroll
    for (int q = 0; q < 4; ++q) Y[q][0] = Y[q][1] = Y[q][2] = 0.f;

    const float4* A4 = reinterpret_cast<const float4*>(Ap);
    const float4* B4 = reinterpret_cast<const float4*>(Bp);
    const float4* C4 = reinterpret_cast<const float4*>(Cp);
    for (int e4 = 0; e4 < Edim / 4; ++e4) {
        float4 wa[4], wb[4], wc[4];
        #pragma unroll
        for (int q = 0; q < 4; ++q) {
            const int f = q * 64 + fl;
            wa[q] = A4[f * (Edim/4) + e4];
            wb[q] = B4[f * (Edim/4) + e4];
            wc[q] = C4[f * (Edim/4) + e4];
        }
        #pragma unroll
        for (int k = 0; k < 4; ++k) {
            const int e = e4 * 4 + k;
            const float4 p0 = sabc[(cg * Edim + e) * 3 + 0];
            const float4 p1 = sabc[(cg * Edim + e) * 3 + 1];
            const float4 p2 = sabc[(cg * Edim + e) * 3 + 2];
            #pragma unroll
            for (int q = 0; q < 4; ++q) {
                const float Af = comp(wa[q], k), Bf = comp(wb[q], k), Cf = comp(wc[q], k);
                Y[q][0] += Af * p0.x + Bf * p0.w + Cf * p1.z;
                Y[q][1] += Af * p0.y + Bf * p1.x + Cf * p1.w;
                Y[q][2] += Af * p0.z + Bf * p1.y + Cf * p2.x;
            }
        }
    }
    #pragma unroll
    for (int q = 0; q < 4; ++q) {
        const int f = q * 64 + fl;
        ylds[cg * 3 + 0][f] = Y[q][0];
        ylds[cg * 3 + 1][f] = Y[q][1];
        ylds[cg * 3 + 2][f] = Y[q][2];
    }
    __syncthreads();

    float D[4][3];
    #pragma unroll
    for (int q = 0; q < 4; ++q) D[q][0] = D[q][1] = D[q][2] = 0.f;
    const float4* W4 = reinterpret_cast<const float4*>(Wp);
    for (int g4 = 0; g4 < Fdim / 4; ++g4) {
        float4 ww[4];
        #pragma unroll
        for (int q = 0; q < 4; ++q) ww[q] = W4[(q * 64 + fl) * (Fdim/4) + g4];
        const float4 y0 = *reinterpret_cast<const float4*>(&ylds[cg * 3 + 0][g4 * 4]);
        const float4 y1 = *reinterpret_cast<const float4*>(&ylds[cg * 3 + 1][g4 * 4]);
        const float4 y2 = *reinterpret_cast<const float4*>(&ylds[cg * 3 + 2][g4 * 4]);
        #pragma unroll
        for (int k = 0; k < 4; ++k) {
            #pragma unroll
            for (int q = 0; q < 4; ++q) {
                const float Wv = comp(ww[q], k);
                D[q][0] += Wv * comp(y0, k);
                D[q][1] += Wv * comp(y1, k);
                D[q][2] += Wv * comp(y2, k);
            }
        }
    }

    float* outl = reinterpret_cast<float*>(sabc);
    #pragma unroll
    for (int q = 0; q < 4; ++q) {
        const int f = q * 64 + fl;
        const float dot = (Y[q][0]*D[q][0] + Y[q][1]*D[q][1]) + Y[q][2]*D[q][2];
        const float dns = (D[q][0]*D[q][0] + D[q][1]*D[q][1]) + D[q][2]*D[q][2];
        const float s   = dot / (dns + EPSf);
        const bool  pos = (dot >= 0.f);
        #pragma unroll
        for (int i = 0; i < 3; ++i) {
            const float x = Y[q][i], d = D[q][i];
            outl[(f * 3 + i) * 4 + cg] = 0.2f*x + 0.8f*(pos ? x : x - s*d);
        }
    }
    __syncthreads();
    const float4* o4 = reinterpret_cast<const float4*>(outl);
    float4* O4 = reinterpret_cast<float4*>(outp);
    const int c4 = c0 >> 2;
    #pragma unroll
    for (int i = 0; i < 3; ++i)
        O4[((b * Fdim + t) * 3 + i) * (Cdim / 4) + c4] = o4[t * 3 + i];
}

extern "C" void kernel_launch(void* const* d_in, const int* in_sizes, int n_in,
                              void* d_out, int out_size, void* d_ws, size_t ws_size,
                              hipStream_t stream) {
    const float* X  = (const float*)d_in[0];
    const float* J  = (const float*)d_in[1];
    const float* A  = (const float*)d_in[2];
    const float* Bw = (const float*)d_in[3];
    const float* Cw = (const float*)d_in[4];
    const float* W  = (const float*)d_in[5];
    float* out = (float*)d_out;

    constexpr size_t WS_NEED = (size_t)(M_ROWS + W_ROWS) * 8 * sizeof(_Float16);  // 512 KiB
    if (ws_size >= WS_NEED) {
        _Float16* wsM = (_Float16*)d_ws;
        _Float16* wsW = wsM + (size_t)M_ROWS * 8;
        prep_weights_f16<<<(M_ROWS + W_ROWS) / 256, 256, 0, stream>>>(A, Bw, Cw, W, wsM);
        fused_mfma_f16<<<Bdim * Cdim / NT / GROUPS, 1024, 0, stream>>>(X, J, wsM, wsW, out);
    } else {
        fused_cl_lrelu_fp32<<<Bdim * Cdim / 4, 256, 0, stream>>>(X, J, A, Bw, Cw, W, out);
    }
}

// Round 8
// 90.325 us; speedup vs baseline: 1.4797x; 1.4797x over previous
//
#include <hip/hip_runtime.h>

// ComplexLinearAndLeakyReLU — round 8: NT=8 small-tile, max occupancy.
// 2048 blocks x 512 threads; LDS 37.25 KB -> 4 blocks/CU = 32 waves/CU.
// Z cols n = i*8 + s (24 cols in 2 MFMA n-tiles; tile1 cols 8-15 unused).
// Epilogue dot/dns over i via __shfl_xor(8) (bit-exact, commuted adds only).
// Math identical to rounds 4-7 (fp16 MFMA, reciprocal basis, np-exact epilogue).

constexpr float EPSf  = 1e-6f;
constexpr int Bdim = 8, Cdim = 2048, Edim = 256, Fdim = 256;
constexpr int NT  = 8;             // sites per block
constexpr int KC1 = 24;            // GEMM1 K chunks of 32 (K=768)
constexpr int KC2 = 8;             // GEMM2 K chunks of 32 (K=256)
constexpr int ZLD = 776;           // Zt row stride in halves (768 + 8 pad)
constexpr int YLD = 264;           // Yt row stride in halves (256 + 8 pad)
constexpr int NROWS = 24;          // valid n rows (3i x 8s)
constexpr int M_ROWS = KC1 * 16 * 64;
constexpr int W_ROWS = KC2 * 16 * 64;

typedef __attribute__((ext_vector_type(8))) _Float16 half8;
typedef __attribute__((ext_vector_type(4))) _Float16 half4;
typedef __attribute__((ext_vector_type(4))) float    f32x4;

// ---- basis + abc: reciprocal-based (3 divides, 2 sqrts), FMA allowed ----
__device__ __forceinline__ void basis_abc(float Xx, float Xy, float Xz,
                                          float Jx, float Jy, float Jz,
                                          float* a, float* bb, float* cc)
{
    const float jn  = sqrtf(Jx*Jx + Jy*Jy + Jz*Jz) + EPSf;
    const float rj  = 1.0f / jn;
    const float nJx = Jx * rj, nJy = Jy * rj, nJz = Jz * rj;
    const float h   = nJx*nJx + nJy*nJy;
    const float Uz  = -h / (nJz + EPSf);
    const float un  = sqrtf(h + Uz*Uz) + EPSf;
    const float ru  = 1.0f / un;
    const float nUx = nJx * ru, nUy = nJy * ru, nUz = Uz * ru;
    const float nVx = nUy*nJz - nUz*nJy;
    const float nVy = nUz*nJx - nUx*nJz;
    const float nVz = nUx*nJy - nUy*nJx;
    const float r0 = nUx*Xx + nVx*Xy + nJx*Xz;
    const float r1 = nUy*Xx + nVy*Xy + nJy*Xz;
    const float r2 = nUz*Xx + nVz*Xy + nJz*Xz;
    a[0]  = nUx*r0 + nUy*r1;   a[1]  = nVx*r0 + nVy*r1;   a[2]  = nJx*r0 + nJy*r1;
    bb[0] = nUy*r0 - nUx*r1;   bb[1] = nVy*r0 - nVx*r1;   bb[2] = nJy*r0 - nJx*r1;
    cc[0] = nUz*r2;            cc[1] = nVz*r2;            cc[2] = nJz*r2;
}

// ---------------- weight prep: fp32 -> fp16 in MFMA A-fragment order ----------------
__global__ __launch_bounds__(256)
void prep_weights_f16(const float* __restrict__ Ap, const float* __restrict__ Bp,
                      const float* __restrict__ Cp, const float* __restrict__ Wp,
                      _Float16* __restrict__ ws)
{
    const int tid = blockIdx.x * 256 + threadIdx.x;
    const bool isW = tid >= M_ROWS;
    const int row = isW ? tid - M_ROWS : tid;
    const int l   = row & 63;
    const int ft  = (row >> 6) & 15;
    const int kc  = row >> 10;
    const int f   = ft * 16 + (l & 15);
    const int k0  = kc * 32 + ((l >> 4) << 3);

    const float* src;
    int e0;
    if (isW)            { src = Wp; e0 = k0; }
    else if (k0 < 256)  { src = Ap; e0 = k0; }
    else if (k0 < 512)  { src = Bp; e0 = k0 - 256; }
    else                { src = Cp; e0 = k0 - 512; }

    const float* p = src + f * 256 + e0;
    half8 v;
    #pragma unroll
    for (int j = 0; j < 8; ++j) v[j] = (_Float16)p[j];

    _Float16* dst = ws + (isW ? (size_t)M_ROWS * 8 : 0);
    *reinterpret_cast<half8*>(dst + (size_t)row * 8) = v;
}

// ---------------- fused main kernel: 512 threads = 8 waves, NT=8 ----------------
__global__ __launch_bounds__(512, 8)
void fused_mfma_f16(const float* __restrict__ Xp, const float* __restrict__ Jp,
                    const _Float16* __restrict__ wsM, const _Float16* __restrict__ wsW,
                    float* __restrict__ outp)
{
    // Zt[24][ZLD] fp16 (37,248 B); after GEMM1, aliased as Yt[24][YLD].
    __shared__ __align__(16) _Float16 lds[NROWS * ZLD];

    const int t  = threadIdx.x;
    const long s0 = (long)blockIdx.x * NT;     // flattened b*Cdim + c base
    const int b  = (int)(s0 >> 11);
    const int c0 = (int)(s0 & (Cdim - 1));

    // ---- phase 1: basis + abc -> Zt (fp16); thread = (site, e-quad) ----
    {
        const int site  = t >> 6;              // 0..7
        const int equad = t & 63;
        const int e0    = equad * 4;
        const long sg   = s0 + site;
        const float4* X4 = reinterpret_cast<const float4*>(Xp) + sg * 192 + equad * 3;
        const float4* J4 = reinterpret_cast<const float4*>(Jp) + sg * 192 + equad * 3;
        const float4 xA = X4[0], xB = X4[1], xC = X4[2];
        const float4 jA = J4[0], jB = J4[1], jC = J4[2];
        const float xf[12] = {xA.x,xA.y,xA.z,xA.w, xB.x,xB.y,xB.z,xB.w, xC.x,xC.y,xC.z,xC.w};
        const float jf[12] = {jA.x,jA.y,jA.z,jA.w, jB.x,jB.y,jB.z,jB.w, jC.x,jC.y,jC.z,jC.w};

        half4 za[3], zb[3], zc[3];
        #pragma unroll
        for (int ee = 0; ee < 4; ++ee) {
            float a[3], bb[3], cc[3];
            basis_abc(xf[3*ee], xf[3*ee+1], xf[3*ee+2],
                      jf[3*ee], jf[3*ee+1], jf[3*ee+2], a, bb, cc);
            #pragma unroll
            for (int i = 0; i < 3; ++i) {
                za[i][ee] = (_Float16)a[i];
                zb[i][ee] = (_Float16)bb[i];
                zc[i][ee] = (_Float16)cc[i];
            }
        }
        // Zt[n = i*8+s][k = m*256+e]; m: 0->a(A), 1->b(Bw), 2->c(Cw)
        #pragma unroll
        for (int i = 0; i < 3; ++i) {
            _Float16* rowp = &lds[(i * NT + site) * ZLD];
            *reinterpret_cast<half4*>(rowp +       e0) = za[i];
            *reinterpret_cast<half4*>(rowp + 256 + e0) = zb[i];
            *reinterpret_cast<half4*>(rowp + 512 + e0) = zc[i];
        }
    }
    __syncthreads();

    const int wid = t >> 6;            // wave owns f-tiles wid*2, wid*2+1
    const int l   = t & 63;
    const int lr  = l & 15;
    const int hi  = l >> 4;
    const int lk  = hi * 8;

    // ---- phase 2: GEMM1, Yacc[q][nt] over K=768 ----
    f32x4 Yacc[2][2];
    #pragma unroll
    for (int q = 0; q < 2; ++q)
        #pragma unroll
        for (int nt = 0; nt < 2; ++nt)
            Yacc[q][nt] = f32x4{0.f, 0.f, 0.f, 0.f};

    // clamped B-fragment rows (tile1 lanes lr>=8 map to a valid dummy row)
    const int zr0 = lr;
    const int zr1 = (16 + lr < NROWS) ? (16 + lr) : 0;

    const half8* Mf = reinterpret_cast<const half8*>(wsM);
    for (int kc = 0; kc < KC1; ++kc) {
        half8 af[2];
        #pragma unroll
        for (int q = 0; q < 2; ++q)
            af[q] = Mf[(kc * 16 + wid * 2 + q) * 64 + l];
        half8 zf0 = *reinterpret_cast<const half8*>(&lds[zr0 * ZLD + kc * 32 + lk]);
        half8 zf1 = *reinterpret_cast<const half8*>(&lds[zr1 * ZLD + kc * 32 + lk]);
        #pragma unroll
        for (int q = 0; q < 2; ++q) {
            Yacc[q][0] = __builtin_amdgcn_mfma_f32_16x16x32_f16(af[q], zf0, Yacc[q][0], 0, 0, 0);
            Yacc[q][1] = __builtin_amdgcn_mfma_f32_16x16x32_f16(af[q], zf1, Yacc[q][1], 0, 0, 0);
        }
    }
    __syncthreads();   // all Zt reads done; safe to alias as Yt

    // ---- stage Y as fp16 Yt[n][g] for GEMM2 B-operand ----
    #pragma unroll
    for (int q = 0; q < 2; ++q) {
        const int gcol = (wid * 2 + q) * 16 + hi * 4;   // g index of reg 0
        #pragma unroll
        for (int nt = 0; nt < 2; ++nt) {
            const int row = nt * 16 + lr;
            if (row < NROWS) {
                half4 v = { (_Float16)Yacc[q][nt][0], (_Float16)Yacc[q][nt][1],
                            (_Float16)Yacc[q][nt][2], (_Float16)Yacc[q][nt][3] };
                *reinterpret_cast<half4*>(&lds[row * YLD + gcol]) = v;
            }
        }
    }
    __syncthreads();

    // ---- phase 3: GEMM2, Dacc[q][nt] over K=256 ----
    f32x4 Dacc[2][2];
    #pragma unroll
    for (int q = 0; q < 2; ++q)
        #pragma unroll
        for (int nt = 0; nt < 2; ++nt)
            Dacc[q][nt] = f32x4{0.f, 0.f, 0.f, 0.f};

    const half8* Wf = reinterpret_cast<const half8*>(wsW);
    for (int kc = 0; kc < KC2; ++kc) {
        half8 wf[2];
        #pragma unroll
        for (int q = 0; q < 2; ++q)
            wf[q] = Wf[(kc * 16 + wid * 2 + q) * 64 + l];
        half8 yf0 = *reinterpret_cast<const half8*>(&lds[zr0 * YLD + kc * 32 + lk]);
        half8 yf1 = *reinterpret_cast<const half8*>(&lds[zr1 * YLD + kc * 32 + lk]);
        #pragma unroll
        for (int q = 0; q < 2; ++q) {
            Dacc[q][0] = __builtin_amdgcn_mfma_f32_16x16x32_f16(wf[q], yf0, Dacc[q][0], 0, 0, 0);
            Dacc[q][1] = __builtin_amdgcn_mfma_f32_16x16x32_f16(wf[q], yf1, Dacc[q][1], 0, 0, 0);
        }
    }

    // ---- epilogue: cross-lane i-reduction via shfl_xor(8), np-exact order ----
    // tile0 lane lr<8: (i=0, site lr); lr>=8: (i=1, site lr-8). tile1 lr<8: (i=2, site lr).
    const int s   = lr & 7;
    const bool lo = (lr < 8);
    #pragma unroll
    for (int q = 0; q < 2; ++q) {
        const int fbase = (wid * 2 + q) * 16 + hi * 4;
        #pragma unroll
        for (int r = 0; r < 4; ++r) {
#pragma clang fp contract(off)
            const float xt0 = Yacc[q][0][r], dt0 = Dacc[q][0][r];
            const float xt1 = Yacc[q][1][r], dt1 = Dacc[q][1][r];
            const float p0  = xt0 * dt0;
            const float p0s = p0 + __shfl_xor(p0, 8);     // x0d0 + x1d1
            const float p1o = __shfl_xor(xt1 * dt1, 8);
            const float dot = p0s + (lo ? xt1 * dt1 : p1o);
            const float q0  = dt0 * dt0;
            const float q0s = q0 + __shfl_xor(q0, 8);     // d0^2 + d1^2
            const float q1o = __shfl_xor(dt1 * dt1, 8);
            const float dns = q0s + (lo ? dt1 * dt1 : q1o);
            const float sc  = dot / (dns + EPSf);
            const bool  pos = (dot >= 0.f);
            const int f = fbase + r;
            const long obase = ((long)(b * Fdim + f) * 3) * Cdim + c0 + s;
            const float v0 = 0.2f*xt0 + 0.8f*(pos ? xt0 : xt0 - sc*dt0);
            outp[obase + (lo ? 0 : 1) * Cdim] = v0;
            if (lo) {
                const float v2 = 0.2f*xt1 + 0.8f*(pos ? xt1 : xt1 - sc*dt1);
                outp[obase + 2 * Cdim] = v2;
            }
        }
    }
}

// ---------------- fp32 fallback if ws too small ----------------
__device__ __forceinline__ float comp(const float4& v, int k) {
    return k == 0 ? v.x : k == 1 ? v.y : k == 2 ? v.z : v.w;
}

__global__ __launch_bounds__(256)
void fused_cl_lrelu_fp32(const float* __restrict__ Xp, const float* __restrict__ Jp,
                         const float* __restrict__ Ap, const float* __restrict__ Bp,
                         const float* __restrict__ Cp, const float* __restrict__ Wp,
                         float* __restrict__ outp)
{
    __shared__ float4 sabc[4 * Edim * 3];
    __shared__ float  ylds[4 * 3][Fdim];

    const int t   = threadIdx.x;
    const int s0  = blockIdx.x * 4;
    const int b   = s0 / Cdim;
    const int c0  = s0 % Cdim;

    #pragma unroll
    for (int r = 0; r < 4; ++r) {
        const int e  = t;
        const int idx = ((b * Cdim + c0 + r) * Edim + e) * 3;
        float a[3], bb[3], cc[3];
        basis_abc(Xp[idx], Xp[idx+1], Xp[idx+2], Jp[idx], Jp[idx+1], Jp[idx+2], a, bb, cc);
        const int base = (r * Edim + e) * 3;
        sabc[base + 0] = make_float4(a[0], a[1], a[2], bb[0]);
        sabc[base + 1] = make_float4(bb[1], bb[2], cc[0], cc[1]);
        sabc[base + 2] = make_float4(cc[2], 0.f, 0.f, 0.f);
    }
    __syncthreads();

    const int fl = t & 63;
    const int cg = t >> 6;
    float Y[4][3];
    #pragma unroll
    for (int q = 0; q < 4; ++q) Y[q][0] = Y[q][1] = Y[q][2] = 0.f;

    const float4* A4 = reinterpret_cast<const float4*>(Ap);
    const float4* B4 = reinterpret_cast<const float4*>(Bp);
    const float4* C4 = reinterpret_cast<const float4*>(Cp);
    for (int e4 = 0; e4 < Edim / 4; ++e4) {
        float4 wa[4], wb[4], wc[4];
        #pragma unroll
        for (int q = 0; q < 4; ++q) {
            const int f = q * 64 + fl;
            wa[q] = A4[f * (Edim/4) + e4];
            wb[q] = B4[f * (Edim/4) + e4];
            wc[q] = C4[f * (Edim/4) + e4];
        }
        #pragma unroll
        for (int k = 0; k < 4; ++k) {
            const int e = e4 * 4 + k;
            const float4 p0 = sabc[(cg * Edim + e) * 3 + 0];
            const float4 p1 = sabc[(cg * Edim + e) * 3 + 1];
            const float4 p2 = sabc[(cg * Edim + e) * 3 + 2];
            #pragma unroll
            for (int q = 0; q < 4; ++q) {
                const float Af = comp(wa[q], k), Bf = comp(wb[q], k), Cf = comp(wc[q], k);
                Y[q][0] += Af * p0.x + Bf * p0.w + Cf * p1.z;
                Y[q][1] += Af * p0.y + Bf * p1.x + Cf * p1.w;
                Y[q][2] += Af * p0.z + Bf * p1.y + Cf * p2.x;
            }
        }
    }
    #pragma unroll
    for (int q = 0; q < 4; ++q) {
        const int f = q * 64 + fl;
        ylds[cg * 3 + 0][f] = Y[q][0];
        ylds[cg * 3 + 1][f] = Y[q][1];
        ylds[cg * 3 + 2][f] = Y[q][2];
    }
    __syncthreads();

    float D[4][3];
    #pragma unroll
    for (int q = 0; q < 4; ++q) D[q][0] = D[q][1] = D[q][2] = 0.f;
    const float4* W4 = reinterpret_cast<const float4*>(Wp);
    for (int g4 = 0; g4 < Fdim / 4; ++g4) {
        float4 ww[4];
        #pragma unroll
        for (int q = 0; q < 4; ++q) ww[q] = W4[(q * 64 + fl) * (Fdim/4) + g4];
        const float4 y0 = *reinterpret_cast<const float4*>(&ylds[cg * 3 + 0][g4 * 4]);
        const float4 y1 = *reinterpret_cast<const float4*>(&ylds[cg * 3 + 1][g4 * 4]);
        const float4 y2 = *reinterpret_cast<const float4*>(&ylds[cg * 3 + 2][g4 * 4]);
        #pragma unroll
        for (int k = 0; k < 4; ++k) {
            #pragma unroll
            for (int q = 0; q < 4; ++q) {
                const float Wv = comp(ww[q], k);
                D[q][0] += Wv * comp(y0, k);
                D[q][1] += Wv * comp(y1, k);
                D[q][2] += Wv * comp(y2, k);
            }
        }
    }

    float* outl = reinterpret_cast<float*>(sabc);
    #pragma unroll
    for (int q = 0; q < 4; ++q) {
        const int f = q * 64 + fl;
        const float dot = (Y[q][0]*D[q][0] + Y[q][1]*D[q][1]) + Y[q][2]*D[q][2];
        const float dns = (D[q][0]*D[q][0] + D[q][1]*D[q][1]) + D[q][2]*D[q][2];
        const float s   = dot / (dns + EPSf);
        const bool  pos = (dot >= 0.f);
        #pragma unroll
        for (int i = 0; i < 3; ++i) {
            const float x = Y[q][i], d = D[q][i];
            outl[(f * 3 + i) * 4 + cg] = 0.2f*x + 0.8f*(pos ? x : x - s*d);
        }
    }
    __syncthreads();
    const float4* o4 = reinterpret_cast<const float4*>(outl);
    float4* O4 = reinterpret_cast<float4*>(outp);
    const int c4 = c0 >> 2;
    #pragma unroll
    for (int i = 0; i < 3; ++i)
        O4[((b * Fdim + t) * 3 + i) * (Cdim / 4) + c4] = o4[t * 3 + i];
}

extern "C" void kernel_launch(void* const* d_in, const int* in_sizes, int n_in,
                              void* d_out, int out_size, void* d_ws, size_t ws_size,
                              hipStream_t stream) {
    const float* X  = (const float*)d_in[0];
    const float* J  = (const float*)d_in[1];
    const float* A  = (const float*)d_in[2];
    const float* Bw = (const float*)d_in[3];
    const float* Cw = (const float*)d_in[4];
    const float* W  = (const float*)d_in[5];
    float* out = (float*)d_out;

    constexpr size_t WS_NEED = (size_t)(M_ROWS + W_ROWS) * 8 * sizeof(_Float16);  // 512 KiB
    if (ws_size >= WS_NEED) {
        _Float16* wsM = (_Float16*)d_ws;
        _Float16* wsW = wsM + (size_t)M_ROWS * 8;
        prep_weights_f16<<<(M_ROWS + W_ROWS) / 256, 256, 0, stream>>>(A, Bw, Cw, W, wsM);
        fused_mfma_f16<<<Bdim * Cdim / NT, 512, 0, stream>>>(X, J, wsM, wsW, out);
    } else {
        fused_cl_lrelu_fp32<<<Bdim * Cdim / 4, 256, 0, stream>>>(X, J, A, Bw, Cw, W, out);
    }
}

// Round 9
// 56.654 us; speedup vs baseline: 2.3591x; 1.5943x over previous
//
#include <hip/hip_runtime.h>

// ComplexLinearAndLeakyReLU — round 9: algebraic basis reduction.
// a = X - m(m.X), b = -(m x X), c = m(m.X) with m = (Uz/un, 0, nJz)
// (R's columns orthonormal; nV_z == 0 analytically). ~3.5x fewer basis VALU ops.
// Structure identical to round 5: fp16 MFMA, 512-thread blocks, NT=16,
// 1024 blocks, 2 blocks/CU.

constexpr float EPSf  = 1e-6f;
constexpr int Bdim = 8, Cdim = 2048, Edim = 256, Fdim = 256;
constexpr int NT  = 16;          // sites per block
constexpr int KC1 = 24;          // GEMM1 K chunks of 32 (K=768)
constexpr int KC2 = 8;           // GEMM2 K chunks of 32 (K=256)
constexpr int ZLD = 776;         // Zt row stride in halves (768 + 8 pad)
constexpr int YLD = 264;         // Yt row stride in halves (256 + 8 pad)
constexpr int M_ROWS = KC1 * 16 * 64;   // 24576 fragment rows (M weights)
constexpr int W_ROWS = KC2 * 16 * 64;   // 8192 fragment rows (W weights)

typedef __attribute__((ext_vector_type(8))) _Float16 half8;
typedef __attribute__((ext_vector_type(4))) _Float16 half4;
typedef __attribute__((ext_vector_type(4))) float    f32x4;

// ---- basis + abc via orthonormal-column identity ----
// R rows (nU,nV,nJ) are orthonormal => columns are too. col2 = (nU_z,nV_z,nJ_z),
// and nV_z = nU_x nJ_y - nU_y nJ_x = ru(nJx nJy - nJy nJx) ~ 0. So with
// m = (Uz/un, 0, nJz):  a = X - m(m.X);  b = col0 x col1 applied = -(m x X);
// c = m(m.X). det(R) = -1 => col0 x col1 = -col2. Identity error ~ eps/sqrt(h),
// negligible vs fp16 quantization for this data.
__device__ __forceinline__ void basis_abc(float Xx, float Xy, float Xz,
                                          float Jx, float Jy, float Jz,
                                          float* a, float* bb, float* cc)
{
    const float jn  = sqrtf(Jx*Jx + Jy*Jy + Jz*Jz) + EPSf;
    const float rj  = __builtin_amdgcn_rcpf(jn);
    const float nJz = Jz * rj;
    const float h   = (Jx*Jx + Jy*Jy) * (rj * rj);   // = nJx^2 + nJy^2
    const float Uz  = -h * __builtin_amdgcn_rcpf(nJz + EPSf);
    const float un  = sqrtf(h + Uz*Uz) + EPSf;
    const float mx  = Uz * __builtin_amdgcn_rcpf(un);
    const float mz  = nJz;
    const float t   = mx*Xx + mz*Xz;                  // m . X
    a[0]  = Xx - mx*t;   a[1]  = Xy;            a[2]  = Xz - mz*t;
    bb[0] = mz*Xy;       bb[1] = mx*Xz - mz*Xx; bb[2] = -(mx*Xy);
    cc[0] = mx*t;        cc[1] = 0.f;           cc[2] = mz*t;
}

// ---------------- weight prep: fp32 -> fp16 in MFMA A-fragment order ----------------
// buf[(kc*16 + ft)*64 + lane][j] holds M[ft*16 + (lane&15)][kc*32 + (lane>>4)*8 + j]
__global__ __launch_bounds__(256)
void prep_weights_f16(const float* __restrict__ Ap, const float* __restrict__ Bp,
                      const float* __restrict__ Cp, const float* __restrict__ Wp,
                      _Float16* __restrict__ ws)
{
    const int tid = blockIdx.x * 256 + threadIdx.x;          // 0 .. 32767
    const bool isW = tid >= M_ROWS;
    const int row = isW ? tid - M_ROWS : tid;
    const int l   = row & 63;
    const int ft  = (row >> 6) & 15;
    const int kc  = row >> 10;
    const int f   = ft * 16 + (l & 15);
    const int k0  = kc * 32 + ((l >> 4) << 3);

    const float* src;
    int e0;
    if (isW)            { src = Wp; e0 = k0; }
    else if (k0 < 256)  { src = Ap; e0 = k0; }
    else if (k0 < 512)  { src = Bp; e0 = k0 - 256; }
    else                { src = Cp; e0 = k0 - 512; }

    const float* p = src + f * 256 + e0;
    half8 v;
    #pragma unroll
    for (int j = 0; j < 8; ++j) v[j] = (_Float16)p[j];

    _Float16* dst = ws + (isW ? (size_t)M_ROWS * 8 : 0);
    *reinterpret_cast<half8*>(dst + (size_t)row * 8) = v;
}

// ---------------- fused main kernel: 512 threads = 8 waves ----------------
__global__ __launch_bounds__(512, 4)
void fused_mfma_f16(const float* __restrict__ Xp, const float* __restrict__ Jp,
                    const _Float16* __restrict__ wsM, const _Float16* __restrict__ wsW,
                    float* __restrict__ outp)
{
    // Zt[48][ZLD] fp16 for GEMM1 B-operand; after GEMM1, aliased as Yt[48][YLD].
    __shared__ __align__(16) _Float16 lds[48 * ZLD];   // 74,496 B -> 2 blocks/CU

    const int t  = threadIdx.x;
    const int s0 = blockIdx.x * NT;
    const int b  = s0 >> 11;          // / Cdim
    const int c0 = s0 & (Cdim - 1);

    // ---- phase 1: basis + abc -> Zt (fp16), e-quad per thread, 2 sites each ----
    {
        const int equad = t & 63;     // e0 = 4*equad
        const int sq    = t >> 6;     // 0..7, each handles 2 sites
        const int e0    = equad * 4;
        #pragma unroll
        for (int ss = 0; ss < 2; ++ss) {
            const int s = sq * 2 + ss;
            const long site = (long)(b * Cdim + c0 + s);
            const float4* X4 = reinterpret_cast<const float4*>(Xp) + site * 192 + equad * 3;
            const float4* J4 = reinterpret_cast<const float4*>(Jp) + site * 192 + equad * 3;
            const float4 xA = X4[0], xB = X4[1], xC = X4[2];
            const float4 jA = J4[0], jB = J4[1], jC = J4[2];
            const float xf[12] = {xA.x,xA.y,xA.z,xA.w, xB.x,xB.y,xB.z,xB.w, xC.x,xC.y,xC.z,xC.w};
            const float jf[12] = {jA.x,jA.y,jA.z,jA.w, jB.x,jB.y,jB.z,jB.w, jC.x,jC.y,jC.z,jC.w};

            half4 za[3], zb[3], zc[3];
            #pragma unroll
            for (int ee = 0; ee < 4; ++ee) {
                float a[3], bb[3], cc[3];
                basis_abc(xf[3*ee], xf[3*ee+1], xf[3*ee+2],
                          jf[3*ee], jf[3*ee+1], jf[3*ee+2], a, bb, cc);
                #pragma unroll
                for (int i = 0; i < 3; ++i) {
                    za[i][ee] = (_Float16)a[i];
                    zb[i][ee] = (_Float16)bb[i];
                    zc[i][ee] = (_Float16)cc[i];
                }
            }
            // Zt[n = i*16+s][k = m*256+e]; m: 0->a(A), 1->b(Bw), 2->c(Cw)
            #pragma unroll
            for (int i = 0; i < 3; ++i) {
                _Float16* rowp = &lds[(i * NT + s) * ZLD];
                *reinterpret_cast<half4*>(rowp +       e0) = za[i];
                *reinterpret_cast<half4*>(rowp + 256 + e0) = zb[i];
                *reinterpret_cast<half4*>(rowp + 512 + e0) = zc[i];
            }
        }
    }
    __syncthreads();

    const int wid = t >> 6;          // wave id 0..7: owns f-tiles wid*2, wid*2+1
    const int l   = t & 63;
    const int lr  = l & 15;          // within-tile row/col
    const int lk  = (l >> 4) * 8;    // k-offset of this lane's 8 elements

    // ---- phase 2: GEMM1, Yacc[q][nt] over K=768 ----
    f32x4 Yacc[2][3];
    #pragma unroll
    for (int q = 0; q < 2; ++q)
        #pragma unroll
        for (int nt = 0; nt < 3; ++nt)
            Yacc[q][nt] = f32x4{0.f, 0.f, 0.f, 0.f};

    const half8* Mf = reinterpret_cast<const half8*>(wsM);
    for (int kc = 0; kc < KC1; ++kc) {
        half8 af[2];
        #pragma unroll
        for (int q = 0; q < 2; ++q)
            af[q] = Mf[(kc * 16 + wid * 2 + q) * 64 + l];
        half8 zf[3];
        #pragma unroll
        for (int nt = 0; nt < 3; ++nt)
            zf[nt] = *reinterpret_cast<const half8*>(&lds[(nt * NT + lr) * ZLD + kc * 32 + lk]);
        #pragma unroll
        for (int q = 0; q < 2; ++q)
            #pragma unroll
            for (int nt = 0; nt < 3; ++nt)
                Yacc[q][nt] = __builtin_amdgcn_mfma_f32_16x16x32_f16(af[q], zf[nt], Yacc[q][nt], 0, 0, 0);
    }
    __syncthreads();   // all Zt reads done; safe to alias as Yt

    // ---- stage Y as fp16 Yt[col][row] for GEMM2 B-operand ----
    #pragma unroll
    for (int q = 0; q < 2; ++q) {
        const int row = (wid * 2 + q) * 16 + (l >> 4) * 4;   // g index of reg 0
        #pragma unroll
        for (int nt = 0; nt < 3; ++nt) {
            const int col = nt * NT + lr;
            half4 v = { (_Float16)Yacc[q][nt][0], (_Float16)Yacc[q][nt][1],
                        (_Float16)Yacc[q][nt][2], (_Float16)Yacc[q][nt][3] };
            *reinterpret_cast<half4*>(&lds[col * YLD + row]) = v;
        }
    }
    __syncthreads();

    // ---- phase 3: GEMM2, Dacc[q][nt] over K=256 ----
    f32x4 Dacc[2][3];
    #pragma unroll
    for (int q = 0; q < 2; ++q)
        #pragma unroll
        for (int nt = 0; nt < 3; ++nt)
            Dacc[q][nt] = f32x4{0.f, 0.f, 0.f, 0.f};

    const half8* Wf = reinterpret_cast<const half8*>(wsW);
    for (int kc = 0; kc < KC2; ++kc) {
        half8 af[2];
        #pragma unroll
        for (int q = 0; q < 2; ++q)
            af[q] = Wf[(kc * 16 + wid * 2 + q) * 64 + l];
        half8 yf[3];
        #pragma unroll
        for (int nt = 0; nt < 3; ++nt)
            yf[nt] = *reinterpret_cast<const half8*>(&lds[(nt * NT + lr) * YLD + kc * 32 + lk]);
        #pragma unroll
        for (int q = 0; q < 2; ++q)
            #pragma unroll
            for (int nt = 0; nt < 3; ++nt)
                Dacc[q][nt] = __builtin_amdgcn_mfma_f32_16x16x32_f16(af[q], yf[nt], Dacc[q][nt], 0, 0, 0);
    }

    // ---- epilogue: leaky projection (np-exact op order), direct stores ----
    #pragma unroll
    for (int q = 0; q < 2; ++q) {
        const int fbase = (wid * 2 + q) * 16 + (l >> 4) * 4;
        #pragma unroll
        for (int r = 0; r < 4; ++r) {
#pragma clang fp contract(off)
            const float x0 = Yacc[q][0][r], x1 = Yacc[q][1][r], x2 = Yacc[q][2][r];
            const float d0 = Dacc[q][0][r], d1 = Dacc[q][1][r], d2 = Dacc[q][2][r];
            const float dot = (x0*d0 + x1*d1) + x2*d2;
            const float dns = (d0*d0 + d1*d1) + d2*d2;
            const float sc  = dot / (dns + EPSf);
            const bool  pos = (dot >= 0.f);
            const int f = fbase + r;
            const long obase = ((long)(b * Fdim + f) * 3) * Cdim + c0 + lr;
            const float c0v = pos ? x0 : (x0 - sc*d0);
            const float c1v = pos ? x1 : (x1 - sc*d1);
            const float c2v = pos ? x2 : (x2 - sc*d2);
            outp[obase + 0 * Cdim] = 0.2f*x0 + 0.8f*c0v;
            outp[obase + 1 * Cdim] = 0.2f*x1 + 0.8f*c1v;
            outp[obase + 2 * Cdim] = 0.2f*x2 + 0.8f*c2v;
        }
    }
}

// ---------------- fp32 fallback if ws too small ----------------
__device__ __forceinline__ float comp(const float4& v, int k) {
    return k == 0 ? v.x : k == 1 ? v.y : k == 2 ? v.z : v.w;
}

__global__ __launch_bounds__(256)
void fused_cl_lrelu_fp32(const float* __restrict__ Xp, const float* __restrict__ Jp,
                         const float* __restrict__ Ap, const float* __restrict__ Bp,
                         const float* __restrict__ Cp, const float* __restrict__ Wp,
                         float* __restrict__ outp)
{
    __shared__ float4 sabc[4 * Edim * 3];
    __shared__ float  ylds[4 * 3][Fdim];

    const int t   = threadIdx.x;
    const int s0  = blockIdx.x * 4;
    const int b   = s0 / Cdim;
    const int c0  = s0 % Cdim;

    #pragma unroll
    for (int r = 0; r < 4; ++r) {
        const int e  = t;
        const int idx = ((b * Cdim + c0 + r) * Edim + e) * 3;
        float a[3], bb[3], cc[3];
        basis_abc(Xp[idx], Xp[idx+1], Xp[idx+2], Jp[idx], Jp[idx+1], Jp[idx+2], a, bb, cc);
        const int base = (r * Edim + e) * 3;
        sabc[base + 0] = make_float4(a[0], a[1], a[2], bb[0]);
        sabc[base + 1] = make_float4(bb[1], bb[2], cc[0], cc[1]);
        sabc[base + 2] = make_float4(cc[2], 0.f, 0.f, 0.f);
    }
    __syncthreads();

    const int fl = t & 63;
    const int cg = t >> 6;
    float Y[4][3];
    #pragma unroll
    for (int q = 0; q < 4; ++q) Y[q][0] = Y[q][1] = Y[q][2] = 0.f;

    const float4* A4 = reinterpret_cast<const float4*>(Ap);
    const float4* B4 = reinterpret_cast<const float4*>(Bp);
    const float4* C4 = reinterpret_cast<const float4*>(Cp);
    for (int e4 = 0; e4 < Edim / 4; ++e4) {
        float4 wa[4], wb[4], wc[4];
        #pragma unroll
        for (int q = 0; q < 4; ++q) {
            const int f = q * 64 + fl;
            wa[q] = A4[f * (Edim/4) + e4];
            wb[q] = B4[f * (Edim/4) + e4];
            wc[q] = C4[f * (Edim/4) + e4];
        }
        #pragma unroll
        for (int k = 0; k < 4; ++k) {
            const int e = e4 * 4 + k;
            const float4 p0 = sabc[(cg * Edim + e) * 3 + 0];
            const float4 p1 = sabc[(cg * Edim + e) * 3 + 1];
            const float4 p2 = sabc[(cg * Edim + e) * 3 + 2];
            #pragma unroll
            for (int q = 0; q < 4; ++q) {
                const float Af = comp(wa[q], k), Bf = comp(wb[q], k), Cf = comp(wc[q], k);
                Y[q][0] += Af * p0.x + Bf * p0.w + Cf * p1.z;
                Y[q][1] += Af * p0.y + Bf * p1.x + Cf * p1.w;
                Y[q][2] += Af * p0.z + Bf * p1.y + Cf * p2.x;
            }
        }
    }
    #pragma unroll
    for (int q = 0; q < 4; ++q) {
        const int f = q * 64 + fl;
        ylds[cg * 3 + 0][f] = Y[q][0];
        ylds[cg * 3 + 1][f] = Y[q][1];
        ylds[cg * 3 + 2][f] = Y[q][2];
    }
    __syncthreads();

    float D[4][3];
    #pragma unroll
    for (int q = 0; q < 4; ++q) D[q][0] = D[q][1] = D[q][2] = 0.f;
    const float4* W4 = reinterpret_cast<const float4*>(Wp);
    for (int g4 = 0; g4 < Fdim / 4; ++g4) {
        float4 ww[4];
        #pragma unroll
        for (int q = 0; q < 4; ++q) ww[q] = W4[(q * 64 + fl) * (Fdim/4) + g4];
        const float4 y0 = *reinterpret_cast<const float4*>(&ylds[cg * 3 + 0][g4 * 4]);
        const float4 y1 = *reinterpret_cast<const float4*>(&ylds[cg * 3 + 1][g4 * 4]);
        const float4 y2 = *reinterpret_cast<const float4*>(&ylds[cg * 3 + 2][g4 * 4]);
        #pragma unroll
        for (int k = 0; k < 4; ++k) {
            #pragma unroll
            for (int q = 0; q < 4; ++q) {
                const float Wv = comp(ww[q], k);
                D[q][0] += Wv * comp(y0, k);
                D[q][1] += Wv * comp(y1, k);
                D[q][2] += Wv * comp(y2, k);
            }
        }
    }

    float* outl = reinterpret_cast<float*>(sabc);
    #pragma unroll
    for (int q = 0; q < 4; ++q) {
        const int f = q * 64 + fl;
        const float dot = (Y[q][0]*D[q][0] + Y[q][1]*D[q][1]) + Y[q][2]*D[q][2];
        const float dns = (D[q][0]*D[q][0] + D[q][1]*D[q][1]) + D[q][2]*D[q][2];
        const float s   = dot / (dns + EPSf);
        const bool  pos = (dot >= 0.f);
        #pragma unroll
        for (int i = 0; i < 3; ++i) {
            const float x = Y[q][i], d = D[q][i];
            outl[(f * 3 + i) * 4 + cg] = 0.2f*x + 0.8f*(pos ? x : x - s*d);
        }
    }
    __syncthreads();
    const float4* o4 = reinterpret_cast<const float4*>(outl);
    float4* O4 = reinterpret_cast<float4*>(outp);
    const int c4 = c0 >> 2;
    #pragma unroll
    for (int i = 0; i < 3; ++i)
        O4[((b * Fdim + t) * 3 + i) * (Cdim / 4) + c4] = o4[t * 3 + i];
}

extern "C" void kernel_launch(void* const* d_in, const int* in_sizes, int n_in,
                              void* d_out, int out_size, void* d_ws, size_t ws_size,
                              hipStream_t stream) {
    const float* X  = (const float*)d_in[0];
    const float* J  = (const float*)d_in[1];
    const float* A  = (const float*)d_in[2];
    const float* Bw = (const float*)d_in[3];
    const float* Cw = (const float*)d_in[4];
    const float* W  = (const float*)d_in[5];
    float* out = (float*)d_out;

    constexpr size_t WS_NEED = (size_t)(M_ROWS + W_ROWS) * 8 * sizeof(_Float16);  // 512 KiB
    if (ws_size >= WS_NEED) {
        _Float16* wsM = (_Float16*)d_ws;
        _Float16* wsW = wsM + (size_t)M_ROWS * 8;
        prep_weights_f16<<<(M_ROWS + W_ROWS) / 256, 256, 0, stream>>>(A, Bw, Cw, W, wsM);
        fused_mfma_f16<<<Bdim * Cdim / NT, 512, 0, stream>>>(X, J, wsM, wsW, out);
    } else {
        fused_cl_lrelu_fp32<<<Bdim * Cdim / 4, 256, 0, stream>>>(X, J, A, Bw, Cw, W, out);
    }
}